// Round 1
// baseline (1556.813 us; speedup 1.0000x reference)
//
#include <hip/hip_runtime.h>
#include <hip/hip_bf16.h>

// LSTM_autoreg fused kernel for MI355X.
// Structure: 256 blocks x 512 threads; block b owns batch rows [16b, 16b+16).
// Whole 2-LSTM pipeline runs inside ONE kernel (batch-parallel, no grid sync).
// Recurrent weights live in registers as MFMA B-fragments (bf16); Wih2 streamed
// from L2 (double-buffered); gates staged fp32 in LDS; c-state in registers.

#define DEV static __device__ __forceinline__

typedef __attribute__((ext_vector_type(8))) short bf16x8;
typedef __attribute__((ext_vector_type(4))) float f32x4;

DEV unsigned short f2bf(float f) {
  unsigned int u = __builtin_bit_cast(unsigned int, f);
  unsigned int r = (u + 0x7fffu + ((u >> 16) & 1u)) >> 16;
  return (unsigned short)r;
}
DEV float bf2f(unsigned short s) {
  return __builtin_bit_cast(float, ((unsigned int)s) << 16);
}
DEV float sigm(float x) {
  float e = __builtin_amdgcn_exp2f(-1.44269504089f * x);
  return __builtin_amdgcn_rcpf(1.0f + e);
}
DEV float tanhf_(float x) {
  float e = __builtin_amdgcn_exp2f(2.88539008178f * x);
  return 1.0f - 2.0f * __builtin_amdgcn_rcpf(1.0f + e);
}

// ---- packed fragment layout in d_ws (ushort/bf16) ----
// frag-group index rest = segbase + kk*48 + nt ; element = rest*512 + lane*8 + j
// seg B1  (rest   0..335): [Whh1 | Wih1 | b1] K=224 (7 kk-groups)
// seg B2H (rest 336..623): Whh2 K=192 (6 kk)
// seg B2X (rest 624..911): Wih2 K=192 (6 kk)
#define SEG_B2H 336
#define SEG_B2X 624
#define PACK_TOTAL (912 * 512)          // 466944 ushort
#define HS1_BYTE_OFF (1u << 20)         // hs1 at +1 MB in d_ws

__global__ void pack_kernel(const float* __restrict__ Wih1,
                            const float* __restrict__ Whh1,
                            const float* __restrict__ b1,
                            const float* __restrict__ Wih2,
                            const float* __restrict__ Whh2,
                            unsigned short* __restrict__ pw) {
  int idx = blockIdx.x * 256 + threadIdx.x;          // 0..466943
  int j = idx & 7;
  int lane = (idx >> 3) & 63;
  int rest = idx >> 9;
  int n, k; float v;
  if (rest < SEG_B2H) {
    int kk = rest / 48, nt = rest % 48;
    n = nt * 16 + (lane & 15);
    k = kk * 32 + (lane >> 4) * 8 + j;               // 0..223
    if (k < 192) v = Whh1[n * 192 + k];
    else { int t = k - 192; v = (t < 31) ? Wih1[n * 31 + t] : b1[n]; }
  } else if (rest < SEG_B2X) {
    int r2 = rest - SEG_B2H; int kk = r2 / 48, nt = r2 % 48;
    n = nt * 16 + (lane & 15);
    k = kk * 32 + (lane >> 4) * 8 + j;
    v = Whh2[n * 192 + k];
  } else {
    int r2 = rest - SEG_B2X; int kk = r2 / 48, nt = r2 % 48;
    n = nt * 16 + (lane & 15);
    k = kk * 32 + (lane >> 4) * 8 + j;
    v = Wih2[n * 192 + k];
  }
  pw[idx] = f2bf(v);
}

__global__ __launch_bounds__(512, 2) void lstm_main(
    const float* __restrict__ xlev,        // [4096,60,15]
    const float* __restrict__ xsfc,        // [4096,24]
    const float* __restrict__ hmem,        // [4096,60,16]
    const float* __restrict__ xmean_lev, const float* __restrict__ xdiv_lev,   // [60,15]
    const float* __restrict__ xmean_sca, const float* __restrict__ xdiv_sca,   // [24]
    const float* __restrict__ yscale_lev,  // [60,5]
    const float* __restrict__ yscale_sca,  // [5]
    const float* __restrict__ b2,          // [768]
    const float* __restrict__ Wsfc1, const float* __restrict__ bsfc1,
    const float* __restrict__ Wsfc2, const float* __restrict__ bsfc2,
    const float* __restrict__ Wtoa1, const float* __restrict__ btoa1,
    const float* __restrict__ Wtoa2, const float* __restrict__ btoa2,
    const float* __restrict__ Wlat, const float* __restrict__ blat,   // [16,192],[16]
    const float* __restrict__ Wout, const float* __restrict__ bout,   // [5,16],[5]
    const float* __restrict__ Wsfcout, const float* __restrict__ bsfcout, // [5,192],[5]
    const unsigned short* __restrict__ pw,
    unsigned short* __restrict__ hs1g,     // [256][60][3072] bf16
    float* __restrict__ out, float* __restrict__ outsfc, float* __restrict__ latout) {

  // LDS: gates fp32 (stride 772 -> 2-way-free banks), A-matrix bf16 [16][392]
  // (cols 0..191 = h, 192.. = x / hs1, stride 784B = 16B-aligned rows)
  __shared__ float g_lds[16 * 772];                         // 49408 B
  __shared__ __align__(16) unsigned short a_lds[16 * 392];  // 12544 B
  __shared__ float misc[16 * 24];                           // sn, then lat   1536 B
  __shared__ float toa_lds[32];                             // 128 B

  const int tid = threadIdx.x;
  const int lane = tid & 63;
  const int wv = tid >> 6;         // wave 0..7, owns gate cols [wv*96, wv*96+96)
  const int bid = blockIdx.x;
  const int r0 = bid * 16;

  // per-thread gate-element mapping: elems idx = tid + 512*e over 16x192
  int erow[6], ecol[6];
  #pragma unroll
  for (int e = 0; e < 6; ++e) { int idx = tid + 512 * e; erow[e] = idx / 192; ecol[e] = idx % 192; }

  // ---- sn = (x_sfc - mean)/div ----
  if (tid < 384) {
    int r = tid / 24, j = tid % 24;
    misc[tid] = (xsfc[(r0 + r) * 24 + j] - xmean_sca[j]) / xdiv_sca[j];
  }
  __syncthreads();
  if (tid < 32) toa_lds[tid] = misc[(tid >> 1) * 24 + (tid & 1)];

  // ---- h0/c0 = tanh(sn @ Wsfc{1,2}.T + b) ----
  float c[6];
  #pragma unroll
  for (int e = 0; e < 6; ++e) {
    int row = erow[e], col = ecol[e];
    float a1 = bsfc1[col], a2 = bsfc2[col];
    for (int k = 0; k < 24; ++k) {
      float s = misc[row * 24 + k];
      a1 = fmaf(s, Wsfc1[col * 24 + k], a1);
      a2 = fmaf(s, Wsfc2[col * 24 + k], a2);
    }
    a_lds[row * 392 + col] = f2bf(tanhf_(a1));
    c[e] = tanhf_(a2);
  }

  // ---- LSTM1 weights -> registers (42 frags = 168 VGPR) ----
  bf16x8 w1[7][6];
  #pragma unroll
  for (int kk = 0; kk < 7; ++kk)
    #pragma unroll
    for (int nt = 0; nt < 6; ++nt)
      w1[kk][nt] = *(const bf16x8*)&pw[((kk * 48 + wv * 6 + nt) * 64 + lane) * 8];
  __syncthreads();

  // =============== Phase A: LSTM1, levels 59 -> 0 ===============
  for (int l = 59; l >= 0; --l) {
    { // stage x row-slice: cols 192..223 = [xn(15) | hmem(16) | 1.0 bias slot]
      int r = tid >> 5, j = tid & 31;
      float v;
      if (j < 15)      v = (xlev[((r0 + r) * 60 + l) * 15 + j] - xmean_lev[l * 15 + j]) / xdiv_lev[l * 15 + j];
      else if (j < 31) v = hmem[((r0 + r) * 60 + l) * 16 + (j - 15)];
      else             v = 1.0f;
      a_lds[r * 392 + 192 + j] = f2bf(v);
    }
    __syncthreads();

    f32x4 acc[6];
    #pragma unroll
    for (int nt = 0; nt < 6; ++nt) acc[nt] = (f32x4){0.f, 0.f, 0.f, 0.f};
    #pragma unroll
    for (int kk = 0; kk < 7; ++kk) {
      const bf16x8 af = *(const bf16x8*)&a_lds[(lane & 15) * 392 + kk * 32 + (lane >> 4) * 8];
      #pragma unroll
      for (int nt = 0; nt < 6; ++nt)
        acc[nt] = __builtin_amdgcn_mfma_f32_16x16x32_bf16(af, w1[kk][nt], acc[nt], 0, 0, 0);
    }
    #pragma unroll
    for (int nt = 0; nt < 6; ++nt)
      #pragma unroll
      for (int q = 0; q < 4; ++q)
        g_lds[((lane >> 4) * 4 + q) * 772 + wv * 96 + nt * 16 + (lane & 15)] = acc[nt][q];
    __syncthreads();

    #pragma unroll
    for (int e = 0; e < 6; ++e) {
      int row = erow[e], col = ecol[e];
      float gi = g_lds[row * 772 + col];          // bias already folded via k=223
      float gf = g_lds[row * 772 + 192 + col];
      float gg = g_lds[row * 772 + 384 + col];
      float go = g_lds[row * 772 + 576 + col];
      c[e] = sigm(gf) * c[e] + sigm(gi) * tanhf_(gg);
      float hv = sigm(go) * tanhf_(c[e]);
      unsigned short hb = f2bf(hv);
      a_lds[row * 392 + col] = hb;
      hs1g[(bid * 60 + l) * 3072 + tid + 512 * e] = hb;
    }
    // no barrier needed: next stage writes disjoint region; stage-barrier orders all
  }

  // =============== Phase C init: h02/c02 from toa ===============
  #pragma unroll
  for (int e = 0; e < 6; ++e) {
    int row = erow[e], col = ecol[e];
    float t0 = toa_lds[row * 2], t1 = toa_lds[row * 2 + 1];
    float a1 = fmaf(t0, Wtoa1[col * 2], fmaf(t1, Wtoa1[col * 2 + 1], btoa1[col]));
    float a2 = fmaf(t0, Wtoa2[col * 2], fmaf(t1, Wtoa2[col * 2 + 1], btoa2[col]));
    a_lds[row * 392 + col] = f2bf(tanhf_(a1));
    c[e] = tanhf_(a2);
  }
  // Whh2 -> registers (36 frags = 144 VGPR); w1 dead, regs reused
  bf16x8 w2[6][6];
  #pragma unroll
  for (int kk = 0; kk < 6; ++kk)
    #pragma unroll
    for (int nt = 0; nt < 6; ++nt)
      w2[kk][nt] = *(const bf16x8*)&pw[((SEG_B2H + kk * 48 + wv * 6 + nt) * 64 + lane) * 8];

  // =============== Phase C: LSTM2 levels 0 -> 59, fused epilogue ===============
  for (int l = 0; l < 60; ++l) {
    #pragma unroll
    for (int e = 0; e < 6; ++e)
      a_lds[erow[e] * 392 + 192 + ecol[e]] = hs1g[(bid * 60 + l) * 3072 + tid + 512 * e];
    __syncthreads();

    // prefetch first 2 Wih2 kk-groups (streamed, L2-hot, constant addresses)
    bf16x8 wx[2][6];
    #pragma unroll
    for (int nt = 0; nt < 6; ++nt)
      wx[0][nt] = *(const bf16x8*)&pw[((SEG_B2X + 0 * 48 + wv * 6 + nt) * 64 + lane) * 8];
    #pragma unroll
    for (int nt = 0; nt < 6; ++nt)
      wx[1][nt] = *(const bf16x8*)&pw[((SEG_B2X + 1 * 48 + wv * 6 + nt) * 64 + lane) * 8];

    f32x4 acc[6];
    #pragma unroll
    for (int nt = 0; nt < 6; ++nt) acc[nt] = (f32x4){0.f, 0.f, 0.f, 0.f};
    // h2 @ Whh2.T  (register weights) -- also covers prefetch latency
    #pragma unroll
    for (int kk = 0; kk < 6; ++kk) {
      const bf16x8 af = *(const bf16x8*)&a_lds[(lane & 15) * 392 + kk * 32 + (lane >> 4) * 8];
      #pragma unroll
      for (int nt = 0; nt < 6; ++nt)
        acc[nt] = __builtin_amdgcn_mfma_f32_16x16x32_bf16(af, w2[kk][nt], acc[nt], 0, 0, 0);
    }
    // hs1_l @ Wih2.T (streamed weights, 2-deep rolling prefetch)
    #pragma unroll
    for (int g = 0; g < 6; ++g) {
      const bf16x8 af = *(const bf16x8*)&a_lds[(lane & 15) * 392 + 192 + g * 32 + (lane >> 4) * 8];
      #pragma unroll
      for (int nt = 0; nt < 6; ++nt)
        acc[nt] = __builtin_amdgcn_mfma_f32_16x16x32_bf16(af, wx[g & 1][nt], acc[nt], 0, 0, 0);
      if (g < 4) {
        #pragma unroll
        for (int nt = 0; nt < 6; ++nt)
          wx[g & 1][nt] = *(const bf16x8*)&pw[((SEG_B2X + (g + 2) * 48 + wv * 6 + nt) * 64 + lane) * 8];
      }
    }
    #pragma unroll
    for (int nt = 0; nt < 6; ++nt)
      #pragma unroll
      for (int q = 0; q < 4; ++q)
        g_lds[((lane >> 4) * 4 + q) * 772 + wv * 96 + nt * 16 + (lane & 15)] = acc[nt][q];
    __syncthreads();

    #pragma unroll
    for (int e = 0; e < 6; ++e) {
      int row = erow[e], col = ecol[e];
      float gi = g_lds[row * 772 + col]       + b2[col];
      float gf = g_lds[row * 772 + 192 + col] + b2[192 + col];
      float gg = g_lds[row * 772 + 384 + col] + b2[384 + col];
      float go = g_lds[row * 772 + 576 + col] + b2[576 + col];
      c[e] = sigm(gf) * c[e] + sigm(gi) * tanhf_(gg);
      a_lds[row * 392 + col] = f2bf(sigm(go) * tanhf_(c[e]));
    }
    __syncthreads();   // h2 (=hs2_l) ready in a_lds

    // epilogue: lat = hs2 @ Wlat.T + blat ; out = (lat @ Wout.T + bout)/yscale
    if (tid < 256) {
      int r = tid >> 4, cc = tid & 15;
      float lv = blat[cc];
      for (int k = 0; k < 192; k += 8) {
        #pragma unroll
        for (int jj = 0; jj < 8; ++jj)
          lv = fmaf(bf2f(a_lds[r * 392 + k + jj]), Wlat[cc * 192 + k + jj], lv);
      }
      latout[((r0 + r) * 60 + l) * 16 + cc] = lv;
      misc[r * 16 + cc] = lv;
    }
    __syncthreads();
    if (tid < 80) {
      int r = tid / 5, y = tid % 5;
      float ov = bout[y];
      #pragma unroll
      for (int k = 0; k < 16; ++k) ov = fmaf(misc[r * 16 + k], Wout[y * 16 + k], ov);
      out[((r0 + r) * 60 + l) * 5 + y] = ov / yscale_lev[l * 5 + y];
    }
  }

  // ---- out_sfc from h_last (still in a_lds cols 0..191) ----
  if (tid < 80) {
    int r = tid / 5, y = tid % 5;
    float ov = bsfcout[y];
    for (int k = 0; k < 192; ++k)
      ov = fmaf(bf2f(a_lds[r * 392 + k]), Wsfcout[y * 192 + k], ov);
    outsfc[(r0 + r) * 5 + y] = ov / yscale_sca[y];
  }
}

extern "C" void kernel_launch(void* const* d_in, const int* in_sizes, int n_in,
                              void* d_out, int out_size, void* d_ws, size_t ws_size,
                              hipStream_t stream) {
  (void)in_sizes; (void)n_in; (void)out_size;

  const float* xlev      = (const float*)d_in[0];
  const float* xsfc      = (const float*)d_in[1];
  const float* hmem      = (const float*)d_in[2];
  const float* xmean_lev = (const float*)d_in[3];
  const float* xdiv_lev  = (const float*)d_in[4];
  const float* xmean_sca = (const float*)d_in[5];
  const float* xdiv_sca  = (const float*)d_in[6];
  const float* yscale_lev= (const float*)d_in[7];
  const float* yscale_sca= (const float*)d_in[8];
  const float* Wih1      = (const float*)d_in[9];
  const float* Whh1      = (const float*)d_in[10];
  const float* b1        = (const float*)d_in[11];
  const float* Wih2      = (const float*)d_in[12];
  const float* Whh2      = (const float*)d_in[13];
  const float* b2        = (const float*)d_in[14];
  const float* Wsfc1     = (const float*)d_in[15];
  const float* bsfc1     = (const float*)d_in[16];
  const float* Wsfc2     = (const float*)d_in[17];
  const float* bsfc2     = (const float*)d_in[18];
  const float* Wtoa1     = (const float*)d_in[19];
  const float* btoa1     = (const float*)d_in[20];
  const float* Wtoa2     = (const float*)d_in[21];
  const float* btoa2     = (const float*)d_in[22];
  const float* Wlat      = (const float*)d_in[23];
  const float* blat      = (const float*)d_in[24];
  const float* Wout      = (const float*)d_in[25];
  const float* bout      = (const float*)d_in[26];
  const float* Wsfcout   = (const float*)d_in[27];
  const float* bsfcout   = (const float*)d_in[28];

  // ws layout: [0, 933888) packed weight frags ; [1 MB, 1 MB + 94.37 MB) hs1 bf16
  const size_t need = (size_t)HS1_BYTE_OFF + (size_t)4096 * 60 * 192 * 2;
  if (ws_size < need) return;   // ws too small: fail validation cleanly, not a fault

  unsigned short* pw   = (unsigned short*)d_ws;
  unsigned short* hs1g = (unsigned short*)((char*)d_ws + HS1_BYTE_OFF);
  float* out    = (float*)d_out;
  float* outsfc = out + (size_t)4096 * 60 * 5;
  float* latout = outsfc + (size_t)4096 * 5;

  hipLaunchKernelGGL(pack_kernel, dim3(PACK_TOTAL / 256), dim3(256), 0, stream,
                     Wih1, Whh1, b1, Wih2, Whh2, pw);
  hipLaunchKernelGGL(lstm_main, dim3(256), dim3(512), 0, stream,
                     xlev, xsfc, hmem, xmean_lev, xdiv_lev, xmean_sca, xdiv_sca,
                     yscale_lev, yscale_sca, b2,
                     Wsfc1, bsfc1, Wsfc2, bsfc2, Wtoa1, btoa1, Wtoa2, btoa2,
                     Wlat, blat, Wout, bout, Wsfcout, bsfcout,
                     pw, hs1g, out, outsfc, latout);
}

// Round 2
// 1470.832 us; speedup vs baseline: 1.0585x; 1.0585x over previous
//
#include <hip/hip_runtime.h>
#include <hip/hip_bf16.h>

// LSTM_autoreg fused kernel for MI355X.  R2: non-temporal streaming + cross-level
// software prefetch.  Diagnosis from R1: 2.17 GB HBM traffic (ideal ~250 MB) --
// hs1g stream evicted packed weights from L2, Wih2 re-fetched from HBM every
// level at ~900cyc latency with 2 waves/SIMD.  Fixes: (a) NT hints on all
// streaming loads/stores so weights stay L2-resident, (b) prefetch next level's
// hs1/x into regs during current level's compute, (c) interleave register-Whh2
// MFMAs with streamed-Wih2 groups for >=240cyc load-use distance.

#define DEV static __device__ __forceinline__

typedef __attribute__((ext_vector_type(8))) short bf16x8;
typedef __attribute__((ext_vector_type(4))) float f32x4;

DEV unsigned short f2bf(float f) {
  unsigned int u = __builtin_bit_cast(unsigned int, f);
  unsigned int r = (u + 0x7fffu + ((u >> 16) & 1u)) >> 16;
  return (unsigned short)r;
}
DEV float bf2f(unsigned short s) {
  return __builtin_bit_cast(float, ((unsigned int)s) << 16);
}
DEV float sigm(float x) {
  float e = __builtin_amdgcn_exp2f(-1.44269504089f * x);
  return __builtin_amdgcn_rcpf(1.0f + e);
}
DEV float tanhf_(float x) {
  float e = __builtin_amdgcn_exp2f(2.88539008178f * x);
  return 1.0f - 2.0f * __builtin_amdgcn_rcpf(1.0f + e);
}

// ---- packed fragment layout in d_ws (ushort/bf16) ----
// frag-group index rest = segbase + kk*48 + nt ; element = rest*512 + lane*8 + j
// seg B1  (rest   0..335): [Whh1 | Wih1 | b1] K=224 (7 kk-groups)
// seg B2H (rest 336..623): Whh2 K=192 (6 kk)
// seg B2X (rest 624..911): Wih2 K=192 (6 kk)
#define SEG_B2H 336
#define SEG_B2X 624
#define PACK_TOTAL (912 * 512)          // 466944 ushort
#define HS1_BYTE_OFF (1u << 20)         // hs1 at +1 MB in d_ws

__global__ void pack_kernel(const float* __restrict__ Wih1,
                            const float* __restrict__ Whh1,
                            const float* __restrict__ b1,
                            const float* __restrict__ Wih2,
                            const float* __restrict__ Whh2,
                            unsigned short* __restrict__ pw) {
  int idx = blockIdx.x * 256 + threadIdx.x;          // 0..466943
  int j = idx & 7;
  int lane = (idx >> 3) & 63;
  int rest = idx >> 9;
  int n, k; float v;
  if (rest < SEG_B2H) {
    int kk = rest / 48, nt = rest % 48;
    n = nt * 16 + (lane & 15);
    k = kk * 32 + (lane >> 4) * 8 + j;               // 0..223
    if (k < 192) v = Whh1[n * 192 + k];
    else { int t = k - 192; v = (t < 31) ? Wih1[n * 31 + t] : b1[n]; }
  } else if (rest < SEG_B2X) {
    int r2 = rest - SEG_B2H; int kk = r2 / 48, nt = r2 % 48;
    n = nt * 16 + (lane & 15);
    k = kk * 32 + (lane >> 4) * 8 + j;
    v = Whh2[n * 192 + k];
  } else {
    int r2 = rest - SEG_B2X; int kk = r2 / 48, nt = r2 % 48;
    n = nt * 16 + (lane & 15);
    k = kk * 32 + (lane >> 4) * 8 + j;
    v = Wih2[n * 192 + k];
  }
  pw[idx] = f2bf(v);
}

__global__ __launch_bounds__(512, 2) void lstm_main(
    const float* __restrict__ xlev,        // [4096,60,15]
    const float* __restrict__ xsfc,        // [4096,24]
    const float* __restrict__ hmem,        // [4096,60,16]
    const float* __restrict__ xmean_lev, const float* __restrict__ xdiv_lev,   // [60,15]
    const float* __restrict__ xmean_sca, const float* __restrict__ xdiv_sca,   // [24]
    const float* __restrict__ yscale_lev,  // [60,5]
    const float* __restrict__ yscale_sca,  // [5]
    const float* __restrict__ b2,          // [768]
    const float* __restrict__ Wsfc1, const float* __restrict__ bsfc1,
    const float* __restrict__ Wsfc2, const float* __restrict__ bsfc2,
    const float* __restrict__ Wtoa1, const float* __restrict__ btoa1,
    const float* __restrict__ Wtoa2, const float* __restrict__ btoa2,
    const float* __restrict__ Wlat, const float* __restrict__ blat,   // [16,192],[16]
    const float* __restrict__ Wout, const float* __restrict__ bout,   // [5,16],[5]
    const float* __restrict__ Wsfcout, const float* __restrict__ bsfcout, // [5,192],[5]
    const unsigned short* __restrict__ pw,
    unsigned short* __restrict__ hs1g,     // [256][60][3072] bf16 == [16][192] row-major per level
    float* __restrict__ out, float* __restrict__ outsfc, float* __restrict__ latout) {

  // LDS: gates fp32 (stride 772), A-matrix bf16 [16][392] (cols 0..191 = h,
  // 192.. = x / hs1; row stride 784B keeps ds_read_b128 at free 2-way conflicts)
  __shared__ float g_lds[16 * 772];                         // 49408 B
  __shared__ __align__(16) unsigned short a_lds[16 * 392];  // 12544 B
  __shared__ float misc[16 * 24];                           // sn, then lat
  __shared__ float toa_lds[32];

  const int tid = threadIdx.x;
  const int lane = tid & 63;
  const int wv = tid >> 6;         // wave 0..7, owns gate cols [wv*96, wv*96+96)
  const int bid = blockIdx.x;
  const int r0 = bid * 16;

  // per-thread gate-element mapping: elems idx = tid + 512*e over 16x192
  int erow[6], ecol[6];
  #pragma unroll
  for (int e = 0; e < 6; ++e) { int idx = tid + 512 * e; erow[e] = idx / 192; ecol[e] = idx % 192; }

  // ---- sn = (x_sfc - mean)/div ----
  if (tid < 384) {
    int r = tid / 24, j = tid % 24;
    misc[tid] = (xsfc[(r0 + r) * 24 + j] - xmean_sca[j]) / xdiv_sca[j];
  }
  __syncthreads();
  if (tid < 32) toa_lds[tid] = misc[(tid >> 1) * 24 + (tid & 1)];

  // ---- h0/c0 = tanh(sn @ Wsfc{1,2}.T + b) ----
  float c[6];
  #pragma unroll
  for (int e = 0; e < 6; ++e) {
    int row = erow[e], col = ecol[e];
    float a1 = bsfc1[col], a2 = bsfc2[col];
    for (int k = 0; k < 24; ++k) {
      float s = misc[row * 24 + k];
      a1 = fmaf(s, Wsfc1[col * 24 + k], a1);
      a2 = fmaf(s, Wsfc2[col * 24 + k], a2);
    }
    a_lds[row * 392 + col] = f2bf(tanhf_(a1));
    c[e] = tanhf_(a2);
  }

  // ---- LSTM1 weights -> registers (42 frags; B-operands can live in AGPRs) ----
  bf16x8 w1[7][6];
  #pragma unroll
  for (int kk = 0; kk < 7; ++kk)
    #pragma unroll
    for (int nt = 0; nt < 6; ++nt)
      w1[kk][nt] = *(const bf16x8*)&pw[((kk * 48 + wv * 6 + nt) * 64 + lane) * 8];

  // prefetch x-slice for level 59 (NT: read-once stream)
  const int xr = tid >> 5, xj = tid & 31;
  float xraw = 0.f;
  if (xj < 15)      xraw = __builtin_nontemporal_load(&xlev[((r0 + xr) * 60 + 59) * 15 + xj]);
  else if (xj < 31) xraw = __builtin_nontemporal_load(&hmem[((r0 + xr) * 60 + 59) * 16 + (xj - 15)]);

  // =============== Phase A: LSTM1, levels 59 -> 0 ===============
  for (int l = 59; l >= 0; --l) {
    { // stage x row-slice from prefetched reg: cols 192..223 = [xn(15)|hmem(16)|1.0]
      float v;
      if (xj < 15)      v = (xraw - xmean_lev[l * 15 + xj]) / xdiv_lev[l * 15 + xj];
      else if (xj < 31) v = xraw;
      else              v = 1.0f;
      a_lds[xr * 392 + 192 + xj] = f2bf(v);
    }
    if (l > 0) { // issue next level's loads; latency hides under MFMA+gates
      if (xj < 15)      xraw = __builtin_nontemporal_load(&xlev[((r0 + xr) * 60 + l - 1) * 15 + xj]);
      else if (xj < 31) xraw = __builtin_nontemporal_load(&hmem[((r0 + xr) * 60 + l - 1) * 16 + (xj - 15)]);
    }
    __syncthreads();

    f32x4 acc[6];
    #pragma unroll
    for (int nt = 0; nt < 6; ++nt) acc[nt] = (f32x4){0.f, 0.f, 0.f, 0.f};
    #pragma unroll
    for (int kk = 0; kk < 7; ++kk) {
      const bf16x8 af = *(const bf16x8*)&a_lds[(lane & 15) * 392 + kk * 32 + (lane >> 4) * 8];
      #pragma unroll
      for (int nt = 0; nt < 6; ++nt)
        acc[nt] = __builtin_amdgcn_mfma_f32_16x16x32_bf16(af, w1[kk][nt], acc[nt], 0, 0, 0);
    }
    #pragma unroll
    for (int nt = 0; nt < 6; ++nt)
      #pragma unroll
      for (int q = 0; q < 4; ++q)
        g_lds[((lane >> 4) * 4 + q) * 772 + wv * 96 + nt * 16 + (lane & 15)] = acc[nt][q];
    __syncthreads();

    #pragma unroll
    for (int e = 0; e < 6; ++e) {
      int row = erow[e], col = ecol[e];
      float gi = g_lds[row * 772 + col];          // bias folded via k=223
      float gf = g_lds[row * 772 + 192 + col];
      float gg = g_lds[row * 772 + 384 + col];
      float go = g_lds[row * 772 + 576 + col];
      c[e] = sigm(gf) * c[e] + sigm(gi) * tanhf_(gg);
      float hv = sigm(go) * tanhf_(c[e]);
      unsigned short hb = f2bf(hv);
      a_lds[row * 392 + col] = hb;
      __builtin_nontemporal_store(hb, &hs1g[(bid * 60 + l) * 3072 + tid + 512 * e]);
    }
    // next iteration's stage-barrier orders everything
  }

  // =============== Phase C init: h02/c02 from toa ===============
  #pragma unroll
  for (int e = 0; e < 6; ++e) {
    int row = erow[e], col = ecol[e];
    float t0 = toa_lds[row * 2], t1 = toa_lds[row * 2 + 1];
    float a1 = fmaf(t0, Wtoa1[col * 2], fmaf(t1, Wtoa1[col * 2 + 1], btoa1[col]));
    float a2 = fmaf(t0, Wtoa2[col * 2], fmaf(t1, Wtoa2[col * 2 + 1], btoa2[col]));
    a_lds[row * 392 + col] = f2bf(tanhf_(a1));
    c[e] = tanhf_(a2);
  }
  // Whh2 -> registers (36 frags); w1 dead, regs reused
  bf16x8 w2[6][6];
  #pragma unroll
  for (int kk = 0; kk < 6; ++kk)
    #pragma unroll
    for (int nt = 0; nt < 6; ++nt)
      w2[kk][nt] = *(const bf16x8*)&pw[((SEG_B2H + kk * 48 + wv * 6 + nt) * 64 + lane) * 8];

  // prefetch hs1 level 0 (NT: written once, read once, don't pollute L2)
  const bf16x8* hs1v = (const bf16x8*)hs1g;
  bf16x8 hv8;
  if (tid < 384) hv8 = __builtin_nontemporal_load(&hs1v[(bid * 60 + 0) * 384 + tid]);

  // =============== Phase C: LSTM2 levels 0 -> 59, fused epilogue ===============
  for (int l = 0; l < 60; ++l) {
    if (tid < 384)  // hs1g level is plain row-major [16][192]
      *(bf16x8*)&a_lds[(tid / 24) * 392 + 192 + (tid % 24) * 8] = hv8;
    if (tid < 384 && l < 59)
      hv8 = __builtin_nontemporal_load(&hs1v[(bid * 60 + l + 1) * 384 + tid]);

    // prefetch streamed Wih2 kk=0,1 (NORMAL loads -- we want these L2-resident)
    bf16x8 wx0[6], wx1[6];
    #pragma unroll
    for (int nt = 0; nt < 6; ++nt)
      wx0[nt] = *(const bf16x8*)&pw[((SEG_B2X + 0 * 48 + wv * 6 + nt) * 64 + lane) * 8];
    #pragma unroll
    for (int nt = 0; nt < 6; ++nt)
      wx1[nt] = *(const bf16x8*)&pw[((SEG_B2X + 1 * 48 + wv * 6 + nt) * 64 + lane) * 8];

    __syncthreads();

    f32x4 acc[6];
    #pragma unroll
    for (int nt = 0; nt < 6; ++nt) acc[nt] = (f32x4){0.f, 0.f, 0.f, 0.f};

    // interleave: register-Whh2 group g covers the L2 latency of streamed wx g+2
    #pragma unroll
    for (int g = 0; g < 6; ++g) {
      const bf16x8 ah = *(const bf16x8*)&a_lds[(lane & 15) * 392 + g * 32 + (lane >> 4) * 8];
      #pragma unroll
      for (int nt = 0; nt < 6; ++nt)
        acc[nt] = __builtin_amdgcn_mfma_f32_16x16x32_bf16(ah, w2[g][nt], acc[nt], 0, 0, 0);
      const bf16x8 ax = *(const bf16x8*)&a_lds[(lane & 15) * 392 + 192 + g * 32 + (lane >> 4) * 8];
      #pragma unroll
      for (int nt = 0; nt < 6; ++nt)
        acc[nt] = __builtin_amdgcn_mfma_f32_16x16x32_bf16(ax, (g & 1) ? wx1[nt] : wx0[nt], acc[nt], 0, 0, 0);
      if (g < 4) {
        #pragma unroll
        for (int nt = 0; nt < 6; ++nt) {
          bf16x8 nw = *(const bf16x8*)&pw[((SEG_B2X + (g + 2) * 48 + wv * 6 + nt) * 64 + lane) * 8];
          if (g & 1) wx1[nt] = nw; else wx0[nt] = nw;
        }
      }
    }
    #pragma unroll
    for (int nt = 0; nt < 6; ++nt)
      #pragma unroll
      for (int q = 0; q < 4; ++q)
        g_lds[((lane >> 4) * 4 + q) * 772 + wv * 96 + nt * 16 + (lane & 15)] = acc[nt][q];
    __syncthreads();

    #pragma unroll
    for (int e = 0; e < 6; ++e) {
      int row = erow[e], col = ecol[e];
      float gi = g_lds[row * 772 + col]       + b2[col];
      float gf = g_lds[row * 772 + 192 + col] + b2[192 + col];
      float gg = g_lds[row * 772 + 384 + col] + b2[384 + col];
      float go = g_lds[row * 772 + 576 + col] + b2[576 + col];
      c[e] = sigm(gf) * c[e] + sigm(gi) * tanhf_(gg);
      a_lds[row * 392 + col] = f2bf(sigm(go) * tanhf_(c[e]));
    }
    __syncthreads();   // h2 (=hs2_l) ready in a_lds

    // epilogue: lat = hs2 @ Wlat.T + blat ; out = (lat @ Wout.T + bout)/yscale
    if (tid < 256) {
      int r = tid >> 4, cc = tid & 15;
      float lv = blat[cc];
      for (int k = 0; k < 192; k += 8) {
        #pragma unroll
        for (int jj = 0; jj < 8; ++jj)
          lv = fmaf(bf2f(a_lds[r * 392 + k + jj]), Wlat[cc * 192 + k + jj], lv);
      }
      __builtin_nontemporal_store(lv, &latout[((r0 + r) * 60 + l) * 16 + cc]);
      misc[r * 16 + cc] = lv;
    }
    __syncthreads();
    if (tid < 80) {
      int r = tid / 5, y = tid % 5;
      float ov = bout[y];
      #pragma unroll
      for (int k = 0; k < 16; ++k) ov = fmaf(misc[r * 16 + k], Wout[y * 16 + k], ov);
      __builtin_nontemporal_store(ov / yscale_lev[l * 5 + y], &out[((r0 + r) * 60 + l) * 5 + y]);
    }
  }

  // ---- out_sfc from h_last (still in a_lds cols 0..191) ----
  if (tid < 80) {
    int r = tid / 5, y = tid % 5;
    float ov = bsfcout[y];
    for (int k = 0; k < 192; ++k)
      ov = fmaf(bf2f(a_lds[r * 392 + k]), Wsfcout[y * 192 + k], ov);
    outsfc[(r0 + r) * 5 + y] = ov / yscale_sca[y];
  }
}

extern "C" void kernel_launch(void* const* d_in, const int* in_sizes, int n_in,
                              void* d_out, int out_size, void* d_ws, size_t ws_size,
                              hipStream_t stream) {
  (void)in_sizes; (void)n_in; (void)out_size;

  const float* xlev      = (const float*)d_in[0];
  const float* xsfc      = (const float*)d_in[1];
  const float* hmem      = (const float*)d_in[2];
  const float* xmean_lev = (const float*)d_in[3];
  const float* xdiv_lev  = (const float*)d_in[4];
  const float* xmean_sca = (const float*)d_in[5];
  const float* xdiv_sca  = (const float*)d_in[6];
  const float* yscale_lev= (const float*)d_in[7];
  const float* yscale_sca= (const float*)d_in[8];
  const float* Wih1      = (const float*)d_in[9];
  const float* Whh1      = (const float*)d_in[10];
  const float* b1        = (const float*)d_in[11];
  const float* Wih2      = (const float*)d_in[12];
  const float* Whh2      = (const float*)d_in[13];
  const float* b2        = (const float*)d_in[14];
  const float* Wsfc1     = (const float*)d_in[15];
  const float* bsfc1     = (const float*)d_in[16];
  const float* Wsfc2     = (const float*)d_in[17];
  const float* bsfc2     = (const float*)d_in[18];
  const float* Wtoa1     = (const float*)d_in[19];
  const float* btoa1     = (const float*)d_in[20];
  const float* Wtoa2     = (const float*)d_in[21];
  const float* btoa2     = (const float*)d_in[22];
  const float* Wlat      = (const float*)d_in[23];
  const float* blat      = (const float*)d_in[24];
  const float* Wout      = (const float*)d_in[25];
  const float* bout      = (const float*)d_in[26];
  const float* Wsfcout   = (const float*)d_in[27];
  const float* bsfcout   = (const float*)d_in[28];

  const size_t need = (size_t)HS1_BYTE_OFF + (size_t)4096 * 60 * 192 * 2;
  if (ws_size < need) return;

  unsigned short* pw   = (unsigned short*)d_ws;
  unsigned short* hs1g = (unsigned short*)((char*)d_ws + HS1_BYTE_OFF);
  float* out    = (float*)d_out;
  float* outsfc = out + (size_t)4096 * 60 * 5;
  float* latout = outsfc + (size_t)4096 * 5;

  hipLaunchKernelGGL(pack_kernel, dim3(PACK_TOTAL / 256), dim3(256), 0, stream,
                     Wih1, Whh1, b1, Wih2, Whh2, pw);
  hipLaunchKernelGGL(lstm_main, dim3(256), dim3(512), 0, stream,
                     xlev, xsfc, hmem, xmean_lev, xdiv_lev, xmean_sca, xdiv_sca,
                     yscale_lev, yscale_sca, b2,
                     Wsfc1, bsfc1, Wsfc2, bsfc2, Wtoa1, btoa1, Wtoa2, btoa2,
                     Wlat, blat, Wout, bout, Wsfcout, bsfcout,
                     pw, hs1g, out, outsfc, latout);
}